// Round 1
// baseline (845.061 us; speedup 1.0000x reference)
//
#include <hip/hip_runtime.h>
#include <hip/hip_bf16.h>
#include <math.h>

#define NROWS 8192
#define DDIM  10000
#define NCLS  100
#define KCHUNKS 4
#define KPER  2500      // KCHUNKS * KPER == DDIM
#define KT    32
#define RPB   128       // rows per block in GEMM
#define LISTCAP 512

#define SCORES_N (NROWS*NCLS)

// ws layout, units of 4-byte elements
#define WS_NORMCLS 0                                   // 128 floats
#define WS_NRMPART 128                                 // KCHUNKS*NROWS floats
#define WS_SCPART  (WS_NRMPART + KCHUNKS*NROWS)        // KCHUNKS*NROWS*NCLS floats
#define WS_CNT_T   (WS_SCPART + KCHUNKS*SCORES_N)      // 128 ints
#define WS_CNT_P   (WS_CNT_T + 128)                    // 128 ints
#define WS_LIST_T  (WS_CNT_P + 128)                    // NCLS*LISTCAP ints
#define WS_LIST_P  (WS_LIST_T + NCLS*LISTCAP)          // NCLS*LISTCAP ints

// ---------------- Phase 0: class norms ----------------
__global__ __launch_bounds__(256) void cls_norms(const float* __restrict__ cls,
                                                 float* __restrict__ ws)
{
    int c = blockIdx.x;
    const float* row = cls + (size_t)c * DDIM;
    float s = 0.f;
    for (int d = threadIdx.x; d < DDIM; d += 256) {
        float v = row[d];
        s = fmaf(v, v, s);
    }
    #pragma unroll
    for (int off = 32; off; off >>= 1) s += __shfl_xor(s, off, 64);
    __shared__ float red[4];
    int w = threadIdx.x >> 6, l = threadIdx.x & 63;
    if (l == 0) red[w] = s;
    __syncthreads();
    if (threadIdx.x == 0) {
        float t = red[0] + red[1] + red[2] + red[3];
        ws[WS_NORMCLS + c] = sqrtf(t);
    }
}

// ---------------- Phase 1: partial-dot GEMM (f32 VALU) ----------------
// block: 256 thr = 4 waves; wave w owns classes [25w, 25w+25)
// lane l owns rows r0+l and r0+64+l ; K split into KCHUNKS chunks (grid.y)
template<int KTLEN>
__device__ __forceinline__ void gemm_tile(
    const float* __restrict__ enc, const float* __restrict__ bbase,
    float (*As)[RPB], int r0, int kg, int l, int q, int rr, int wu,
    float acc0[25], float acc1[25], float& na0, float& na1)
{
    __syncthreads();
    // stage A tile: [KT][RPB] k-major; thread: k-quad q (0..7), row rr (0..31), 4 row passes
    #pragma unroll
    for (int p = 0; p < 4; ++p) {
        int row = rr + p * 32;
        int kq = q * 4;
        float4 v = make_float4(0.f, 0.f, 0.f, 0.f);
        if (kq + 4 <= KTLEN) {
            v = *(const float4*)(enc + (size_t)(r0 + row) * DDIM + kg + kq);
        }
        As[kq + 0][row] = v.x;
        As[kq + 1][row] = v.y;
        As[kq + 2][row] = v.z;
        As[kq + 3][row] = v.w;
    }
    __syncthreads();

    #pragma unroll 2
    for (int k2 = 0; k2 < KTLEN; k2 += 2) {
        float2 bq[25];
        #pragma unroll
        for (int j = 0; j < 25; ++j)
            bq[j] = *(const float2*)(bbase + (size_t)j * DDIM + kg + k2);
        #pragma unroll
        for (int e = 0; e < 2; ++e) {
            float a0 = As[k2 + e][l];
            float a1 = As[k2 + e][64 + l];
            if (wu == 0) { na0 = fmaf(a0, a0, na0); na1 = fmaf(a1, a1, na1); }
            #pragma unroll
            for (int j = 0; j < 25; ++j) {
                float b = e ? bq[j].y : bq[j].x;
                acc0[j] = fmaf(a0, b, acc0[j]);
                acc1[j] = fmaf(a1, b, acc1[j]);
            }
        }
    }
}

__global__ __launch_bounds__(256) void gemm_part(const float* __restrict__ enc,
                                                 const float* __restrict__ cls,
                                                 float* __restrict__ ws)
{
    __shared__ float As[KT][RPB];   // 16 KB
    int tid = threadIdx.x;
    int w = tid >> 6, l = tid & 63;
    int wu = __builtin_amdgcn_readfirstlane(w);
    int q = tid & 7, rr = tid >> 3;
    int r0 = blockIdx.x * RPB;
    int ky = blockIdx.y;
    int kbeg = ky * KPER;
    const float* bbase = cls + (size_t)(wu * 25) * DDIM;

    float acc0[25], acc1[25];
    #pragma unroll
    for (int j = 0; j < 25; ++j) { acc0[j] = 0.f; acc1[j] = 0.f; }
    float na0 = 0.f, na1 = 0.f;

    constexpr int NFULL = KPER / KT;
    constexpr int KREM = KPER - NFULL * KT;
    int kg = kbeg;
    for (int t = 0; t < NFULL; ++t, kg += KT)
        gemm_tile<KT>(enc, bbase, As, r0, kg, l, q, rr, wu, acc0, acc1, na0, na1);
    if constexpr (KREM > 0)
        gemm_tile<KREM>(enc, bbase, As, r0, kg, l, q, rr, wu, acc0, acc1, na0, na1);

    // epilogue: partial dots and partial row-norms (deterministic, no atomics)
    float* scp = ws + WS_SCPART + (size_t)ky * SCORES_N;
    int c0 = wu * 25;
    #pragma unroll
    for (int j = 0; j < 25; ++j) {
        scp[(size_t)(r0 + l) * NCLS + c0 + j]      = acc0[j];
        scp[(size_t)(r0 + 64 + l) * NCLS + c0 + j] = acc1[j];
    }
    if (wu == 0) {
        ws[WS_NRMPART + (size_t)ky * NROWS + r0 + l]      = na0;
        ws[WS_NRMPART + (size_t)ky * NROWS + r0 + 64 + l] = na1;
    }
}

// ---------------- Phase 2: finalize scores, argmax, build class lists ----------------
__global__ __launch_bounds__(256) void finalize(const int* __restrict__ targets,
                                                float* __restrict__ out,
                                                float* __restrict__ ws)
{
    int w = threadIdx.x >> 6, l = threadIdx.x & 63;
    int row = blockIdx.x * 4 + w;
    const float* scp = ws + WS_SCPART;

    float n2 = 0.f;
    #pragma unroll
    for (int ky = 0; ky < KCHUNKS; ++ky) n2 += ws[WS_NRMPART + ky * NROWS + row];
    float ne = sqrtf(n2);

    float best; int bi;
    {
        int c = l;
        float dsum = 0.f;
        #pragma unroll
        for (int ky = 0; ky < KCHUNKS; ++ky)
            dsum += scp[(size_t)ky * SCORES_N + (size_t)row * NCLS + c];
        float s = dsum / (ne * ws[WS_NORMCLS + c]);
        out[(size_t)row * NCLS + c] = s;
        best = s; bi = c;
    }
    if (l + 64 < NCLS) {
        int c = l + 64;
        float dsum = 0.f;
        #pragma unroll
        for (int ky = 0; ky < KCHUNKS; ++ky)
            dsum += scp[(size_t)ky * SCORES_N + (size_t)row * NCLS + c];
        float s = dsum / (ne * ws[WS_NORMCLS + c]);
        out[(size_t)row * NCLS + c] = s;
        if (s > best) { best = s; bi = c; }   // tie keeps smaller index (c > l)
    }
    #pragma unroll
    for (int off = 32; off; off >>= 1) {
        float ov = __shfl_xor(best, off, 64);
        int   oi = __shfl_xor(bi, off, 64);
        if (ov > best || (ov == best && oi < bi)) { best = ov; bi = oi; }
    }
    if (l == 0) {
        int tgt = targets[row];
        if (tgt != bi) {
            int* wsi = (int*)ws;
            int p1 = atomicAdd(wsi + WS_CNT_T + tgt, 1);
            if (p1 < LISTCAP) wsi[WS_LIST_T + tgt * LISTCAP + p1] = row;
            int p2 = atomicAdd(wsi + WS_CNT_P + bi, 1);
            if (p2 < LISTCAP) wsi[WS_LIST_P + bi * LISTCAP + p2] = row;
        }
    }
}

// ---------------- Phase 3: perceptron update ----------------
// block = (d-chunk of 256, class c): sums its class's wrong rows, writes final hv
__global__ __launch_bounds__(256) void update(const float* __restrict__ enc,
                                              const float* __restrict__ cls,
                                              float* __restrict__ out,
                                              const float* __restrict__ ws)
{
    int c = blockIdx.y;
    int d = blockIdx.x * 256 + threadIdx.x;
    if (d >= DDIM) return;
    const int* wsi = (const int*)ws;

    float acc = 0.f;
    int nt = wsi[WS_CNT_T + c]; nt = nt < LISTCAP ? nt : LISTCAP;
    for (int i = 0; i < nt; ++i) {
        int n = wsi[WS_LIST_T + c * LISTCAP + i];
        acc += enc[(size_t)n * DDIM + d];
    }
    int np = wsi[WS_CNT_P + c]; np = np < LISTCAP ? np : LISTCAP;
    for (int i = 0; i < np; ++i) {
        int n = wsi[WS_LIST_P + c * LISTCAP + i];
        acc -= enc[(size_t)n * DDIM + d];
    }
    out[SCORES_N + (size_t)c * DDIM + d] = cls[(size_t)c * DDIM + d] + acc;
}

// ---------------- launch ----------------
extern "C" void kernel_launch(void* const* d_in, const int* in_sizes, int n_in,
                              void* d_out, int out_size, void* d_ws, size_t ws_size,
                              hipStream_t stream)
{
    const float* enc = (const float*)d_in[0];
    const float* cls = (const float*)d_in[1];
    const int*   tgt = (const int*)d_in[2];
    float* out = (float*)d_out;
    float* ws  = (float*)d_ws;

    // zero the list counters (256 ints)
    hipMemsetAsync((char*)d_ws + (size_t)WS_CNT_T * 4, 0, 256 * 4, stream);

    cls_norms<<<NCLS, 256, 0, stream>>>(cls, ws);

    dim3 g1(NROWS / RPB, KCHUNKS);
    gemm_part<<<g1, 256, 0, stream>>>(enc, cls, ws);

    finalize<<<NROWS / 4, 256, 0, stream>>>(tgt, out, ws);

    dim3 g3((DDIM + 255) / 256, NCLS);
    update<<<g3, 256, 0, stream>>>(enc, cls, out, ws);
}

// Round 2
// 448.468 us; speedup vs baseline: 1.8843x; 1.8843x over previous
//
#include <hip/hip_runtime.h>
#include <hip/hip_bf16.h>
#include <math.h>

#define NROWS 8192
#define DDIM  10000
#define NCLS  100
#define LISTCAP 512

#define KSPLIT 2
#define KSTEPS_TOT 313        // ceil(10000/32)
#define KSPLIT_MID 157        // ky0: [0,157), ky1: [157,313)
#define BM 32

#define SCORES_N (NROWS*NCLS)
#define NCHUNK8 1252          // 10016/8
#define BP_CHUNKS (NCHUNK8*128)   // 160256

// ws layout in float (4B) units
#define WS_NORMCLS 0                                   // 128
#define WS_NRM     128                                 // KSPLIT*NROWS
#define WS_SCP     (WS_NRM + KSPLIT*NROWS)             // KSPLIT*NROWS*NCLS
#define WS_CNT_T   (WS_SCP + KSPLIT*SCORES_N)          // 128
#define WS_CNT_P   (WS_CNT_T + 128)                    // 128
#define WS_LIST_T  (WS_CNT_P + 128)                    // NCLS*LISTCAP
#define WS_LIST_P  (WS_LIST_T + NCLS*LISTCAP)          // NCLS*LISTCAP
#define WS_BPH     (WS_LIST_P + NCLS*LISTCAP)          // BP_CHUNKS*8 f16 = BP_CHUNKS*4 floats
#define WS_BPL     (WS_BPH + BP_CHUNKS*4)

typedef _Float16 f16;
typedef f16 f16x4 __attribute__((ext_vector_type(4)));
typedef f16 f16x8 __attribute__((ext_vector_type(8)));
typedef float f32x4 __attribute__((ext_vector_type(4)));

typedef const __attribute__((address_space(1))) void GAS;
typedef __attribute__((address_space(3))) void LAS;

#define SBAR()  __builtin_amdgcn_s_barrier()
#define SCHED() __builtin_amdgcn_sched_barrier(0)

// ---------------- Phase 0: class norms ----------------
__global__ __launch_bounds__(256) void cls_norms(const float* __restrict__ cls,
                                                 float* __restrict__ ws)
{
    int c = blockIdx.x;
    const float* row = cls + (size_t)c * DDIM;
    float s = 0.f;
    for (int d = threadIdx.x; d < DDIM; d += 256) {
        float v = row[d];
        s = fmaf(v, v, s);
    }
    #pragma unroll
    for (int off = 32; off; off >>= 1) s += __shfl_xor(s, off, 64);
    __shared__ float red[4];
    int w = threadIdx.x >> 6, l = threadIdx.x & 63;
    if (l == 0) red[w] = s;
    __syncthreads();
    if (threadIdx.x == 0) {
        float t = red[0] + red[1] + red[2] + red[3];
        ws[WS_NORMCLS + c] = sqrtf(t);
    }
}

// ---------------- Phase 0b: convert class_hvs to fp16 hi/lo, chunked layout ----------------
// chunk c = k8*128 + col holds cls[col][k8*8 .. +7]; zero-padded (col>=100 or k>=10000)
__global__ __launch_bounds__(256) void prep_b(const float* __restrict__ cls,
                                              float* __restrict__ ws)
{
    int c = blockIdx.x * 256 + threadIdx.x;
    if (c >= BP_CHUNKS) return;
    int col = c & 127, k8 = c >> 7;
    f16x8 hi, lo;
    #pragma unroll
    for (int j = 0; j < 8; ++j) {
        int k = k8 * 8 + j;
        float v = (col < NCLS && k < DDIM) ? cls[(size_t)col * DDIM + k] : 0.f;
        f16 h = (f16)v;
        hi[j] = h;
        lo[j] = (f16)(v - (float)h);
    }
    ((f16x8*)(ws + WS_BPH))[c] = hi;
    ((f16x8*)(ws + WS_BPL))[c] = lo;
}

// ---------------- Phase 1: MFMA GEMM with fp16 split ----------------
// grid (256, KSPLIT); block 256 = 4 waves; wave w -> cols [32w,32w+32)
// per block: rows [32*bx, +32), K steps [s_beg, s_end) of 32
__global__ __launch_bounds__(256, 2) void gemm_mfma(const float* __restrict__ enc,
                                                    float* __restrict__ ws)
{
    __shared__ f16 Ah[4*32*8], Al[4*32*8];    // [kg][row][8]
    __shared__ f16 Bh[4*128*8], Bl[4*128*8];  // [kg][col][8]

    int tid = threadIdx.x;
    int w = __builtin_amdgcn_readfirstlane(tid >> 6);
    int l = tid & 63;
    int r0 = blockIdx.x * BM;
    int ky = blockIdx.y;
    int s_beg = ky == 0 ? 0 : KSPLIT_MID;
    int s_end = ky == 0 ? KSPLIT_MID : KSTEPS_TOT;

    // A staging mapping: thread -> (row_a, kq): 4 consecutive f32 of one row
    int row_a = tid >> 3, kq = tid & 7;
    const float* aptr0 = enc + (size_t)(r0 + row_a) * DDIM;
    int awr = (kq >> 1) * 256 + row_a * 8 + (kq & 1) * 4;   // f16 elem offset in Ah/Al

    const f16* bph = (const f16*)(ws + WS_BPH);
    const f16* bpl = (const f16*)(ws + WS_BPL);

    int lane15 = l & 15, lg = l >> 4;
    int aoff = lg * 256 + lane15 * 8;                 // mt=0 frag elem offset
    int boff = lg * 1024 + (w * 32 + lane15) * 8;     // nt=0 frag elem offset

    f32x4 acc[2][2] = {};
    float nsq = 0.f;

    // prologue: load first A tile
    float4 areg = *(const float4*)(aptr0 + s_beg * 32 + kq * 4);

    for (int s = s_beg; s < s_end; ++s) {
        // ---- write phase: convert A regs -> LDS hi/lo ----
        float4 a = areg;
        f16 h0 = (f16)a.x, h1 = (f16)a.y, h2 = (f16)a.z, h3 = (f16)a.w;
        f16x4 hv = {h0, h1, h2, h3};
        f16x4 lv = {(f16)(a.x - (float)h0), (f16)(a.y - (float)h1),
                    (f16)(a.z - (float)h2), (f16)(a.w - (float)h3)};
        nsq = fmaf(a.x, a.x, nsq); nsq = fmaf(a.y, a.y, nsq);
        nsq = fmaf(a.z, a.z, nsq); nsq = fmaf(a.w, a.w, nsq);
        *(f16x4*)&Ah[awr] = hv;
        *(f16x4*)&Al[awr] = lv;

        // ---- B staging: global_load_lds, 4 instrs per wave (2 hi, 2 lo) ----
        {
            size_t sbase = (size_t)s * 4096;  // f16 elems: s*512 chunks * 8
            #pragma unroll
            for (int j = 0; j < 2; ++j) {
                int ioff = (2 * w + j) * 512;  // f16 elems
                __builtin_amdgcn_global_load_lds((GAS*)(bph + sbase + ioff + l * 8),
                                                 (LAS*)&Bh[ioff], 16, 0, 0);
            }
            #pragma unroll
            for (int j = 0; j < 2; ++j) {
                int ioff = (2 * w + j) * 512;
                __builtin_amdgcn_global_load_lds((GAS*)(bpl + sbase + ioff + l * 8),
                                                 (LAS*)&Bl[ioff], 16, 0, 0);
            }
        }
        SCHED();
        // ---- prefetch next A tile (always exactly one load -> vmcnt(1) exact) ----
        {
            int kn = (s + 1) * 32 + kq * 4;
            bool ok = (kn + 4 <= DDIM);
            float4 t = *(const float4*)(aptr0 + (ok ? kn : 0));
            areg = ok ? t : make_float4(0.f, 0.f, 0.f, 0.f);
        }
        SCHED();
        asm volatile("s_waitcnt vmcnt(1) lgkmcnt(0)" ::: "memory");
        SCHED();
        SBAR();

        // ---- read + MFMA phase ----
        f16x8 ah0 = *(const f16x8*)&Ah[aoff];
        f16x8 ah1 = *(const f16x8*)&Ah[aoff + 128];
        f16x8 al0 = *(const f16x8*)&Al[aoff];
        f16x8 al1 = *(const f16x8*)&Al[aoff + 128];
        f16x8 bh0 = *(const f16x8*)&Bh[boff];
        f16x8 bh1 = *(const f16x8*)&Bh[boff + 128];
        f16x8 bl0 = *(const f16x8*)&Bl[boff];
        f16x8 bl1 = *(const f16x8*)&Bl[boff + 128];

        acc[0][0] = __builtin_amdgcn_mfma_f32_16x16x32_f16(ah0, bh0, acc[0][0], 0, 0, 0);
        acc[0][1] = __builtin_amdgcn_mfma_f32_16x16x32_f16(ah0, bh1, acc[0][1], 0, 0, 0);
        acc[1][0] = __builtin_amdgcn_mfma_f32_16x16x32_f16(ah1, bh0, acc[1][0], 0, 0, 0);
        acc[1][1] = __builtin_amdgcn_mfma_f32_16x16x32_f16(ah1, bh1, acc[1][1], 0, 0, 0);
        acc[0][0] = __builtin_amdgcn_mfma_f32_16x16x32_f16(al0, bh0, acc[0][0], 0, 0, 0);
        acc[0][1] = __builtin_amdgcn_mfma_f32_16x16x32_f16(al0, bh1, acc[0][1], 0, 0, 0);
        acc[1][0] = __builtin_amdgcn_mfma_f32_16x16x32_f16(al1, bh0, acc[1][0], 0, 0, 0);
        acc[1][1] = __builtin_amdgcn_mfma_f32_16x16x32_f16(al1, bh1, acc[1][1], 0, 0, 0);
        acc[0][0] = __builtin_amdgcn_mfma_f32_16x16x32_f16(ah0, bl0, acc[0][0], 0, 0, 0);
        acc[0][1] = __builtin_amdgcn_mfma_f32_16x16x32_f16(ah0, bl1, acc[0][1], 0, 0, 0);
        acc[1][0] = __builtin_amdgcn_mfma_f32_16x16x32_f16(ah1, bl0, acc[1][0], 0, 0, 0);
        acc[1][1] = __builtin_amdgcn_mfma_f32_16x16x32_f16(ah1, bl1, acc[1][1], 0, 0, 0);

        SCHED();
        asm volatile("s_waitcnt lgkmcnt(0)" ::: "memory");
        SCHED();
        SBAR();
    }

    // ---- epilogue: partial scores ----
    float* scp = ws + WS_SCP + (size_t)ky * SCORES_N;
    #pragma unroll
    for (int mt = 0; mt < 2; ++mt) {
        #pragma unroll
        for (int nt = 0; nt < 2; ++nt) {
            int gcol = w * 32 + nt * 16 + lane15;
            if (gcol < NCLS) {
                #pragma unroll
                for (int j = 0; j < 4; ++j) {
                    int grow = r0 + mt * 16 + lg * 4 + j;
                    scp[(size_t)grow * NCLS + gcol] = acc[mt][nt][j];
                }
            }
        }
    }

    // ---- row-norm partials: reduce across kq (8 threads per row) ----
    float t = nsq;
    t += __shfl_xor(t, 1, 8);
    t += __shfl_xor(t, 2, 8);
    t += __shfl_xor(t, 4, 8);
    if (kq == 0) ws[WS_NRM + (size_t)ky * NROWS + r0 + row_a] = t;
}

// ---------------- Phase 2: finalize scores, argmax, build class lists ----------------
__global__ __launch_bounds__(256) void finalize(const int* __restrict__ targets,
                                                float* __restrict__ out,
                                                float* __restrict__ ws)
{
    int w = threadIdx.x >> 6, l = threadIdx.x & 63;
    int row = blockIdx.x * 4 + w;
    const float* scp = ws + WS_SCP;

    float n2 = ws[WS_NRM + row] + ws[WS_NRM + NROWS + row];
    float ne = sqrtf(n2);

    float best; int bi;
    {
        int c = l;
        float dsum = scp[(size_t)row * NCLS + c] + scp[(size_t)SCORES_N + (size_t)row * NCLS + c];
        float s = dsum / (ne * ws[WS_NORMCLS + c]);
        out[(size_t)row * NCLS + c] = s;
        best = s; bi = c;
    }
    if (l + 64 < NCLS) {
        int c = l + 64;
        float dsum = scp[(size_t)row * NCLS + c] + scp[(size_t)SCORES_N + (size_t)row * NCLS + c];
        float s = dsum / (ne * ws[WS_NORMCLS + c]);
        out[(size_t)row * NCLS + c] = s;
        if (s > best) { best = s; bi = c; }   // ties keep smaller index
    }
    #pragma unroll
    for (int off = 32; off; off >>= 1) {
        float ov = __shfl_xor(best, off, 64);
        int   oi = __shfl_xor(bi, off, 64);
        if (ov > best || (ov == best && oi < bi)) { best = ov; bi = oi; }
    }
    if (l == 0) {
        int tgt = targets[row];
        if (tgt != bi) {
            int* wsi = (int*)ws;
            int p1 = atomicAdd(wsi + WS_CNT_T + tgt, 1);
            if (p1 < LISTCAP) wsi[WS_LIST_T + tgt * LISTCAP + p1] = row;
            int p2 = atomicAdd(wsi + WS_CNT_P + bi, 1);
            if (p2 < LISTCAP) wsi[WS_LIST_P + bi * LISTCAP + p2] = row;
        }
    }
}

// ---------------- Phase 3: perceptron update ----------------
__global__ __launch_bounds__(256) void update(const float* __restrict__ enc,
                                              const float* __restrict__ cls,
                                              float* __restrict__ out,
                                              const float* __restrict__ ws)
{
    int c = blockIdx.y;
    int d = blockIdx.x * 256 + threadIdx.x;
    if (d >= DDIM) return;
    const int* wsi = (const int*)ws;

    float acc = 0.f;
    int nt = wsi[WS_CNT_T + c]; nt = nt < LISTCAP ? nt : LISTCAP;
    for (int i = 0; i < nt; ++i) {
        int n = wsi[WS_LIST_T + c * LISTCAP + i];
        acc += enc[(size_t)n * DDIM + d];
    }
    int np = wsi[WS_CNT_P + c]; np = np < LISTCAP ? np : LISTCAP;
    for (int i = 0; i < np; ++i) {
        int n = wsi[WS_LIST_P + c * LISTCAP + i];
        acc -= enc[(size_t)n * DDIM + d];
    }
    out[SCORES_N + (size_t)c * DDIM + d] = cls[(size_t)c * DDIM + d] + acc;
}

// ---------------- launch ----------------
extern "C" void kernel_launch(void* const* d_in, const int* in_sizes, int n_in,
                              void* d_out, int out_size, void* d_ws, size_t ws_size,
                              hipStream_t stream)
{
    const float* enc = (const float*)d_in[0];
    const float* cls = (const float*)d_in[1];
    const int*   tgt = (const int*)d_in[2];
    float* out = (float*)d_out;
    float* ws  = (float*)d_ws;

    // zero the list counters (256 ints)
    hipMemsetAsync((char*)d_ws + (size_t)WS_CNT_T * 4, 0, 256 * 4, stream);

    cls_norms<<<NCLS, 256, 0, stream>>>(cls, ws);
    prep_b<<<(BP_CHUNKS + 255) / 256, 256, 0, stream>>>(cls, ws);

    dim3 g1(NROWS / BM, KSPLIT);
    gemm_mfma<<<g1, 256, 0, stream>>>(enc, ws);

    finalize<<<NROWS / 4, 256, 0, stream>>>(tgt, out, ws);

    dim3 g3((DDIM + 255) / 256, NCLS);
    update<<<g3, 256, 0, stream>>>(enc, cls, out, ws);
}

// Round 3
// 345.540 us; speedup vs baseline: 2.4456x; 1.2979x over previous
//
#include <hip/hip_runtime.h>
#include <hip/hip_bf16.h>
#include <math.h>

#define NROWS 8192
#define DDIM  10000
#define NCLS  100
#define LISTCAP 512

#define KSPLIT 4
#define KSTEPS 157            // ceil(10000/64)
#define BM 64
#define BK 64

#define SCORES_N (NROWS*NCLS)
#define NCHUNK8 1256          // 157*8 k-octets (covers k-padding to 10048)
#define BP_CHUNKS (NCHUNK8*128)

// ws layout in float (4B) units
#define WS_NORMCLS 0                                   // 128
#define WS_NRM     128                                 // KSPLIT*NROWS
#define WS_SCP     (WS_NRM + KSPLIT*NROWS)             // KSPLIT*NROWS*NCLS
#define WS_CNT_T   (WS_SCP + KSPLIT*SCORES_N)          // 128
#define WS_CNT_P   (WS_CNT_T + 128)                    // 128
#define WS_LIST_T  (WS_CNT_P + 128)                    // NCLS*LISTCAP
#define WS_LIST_P  (WS_LIST_T + NCLS*LISTCAP)          // NCLS*LISTCAP
#define WS_BPH     (WS_LIST_P + NCLS*LISTCAP)          // BP_CHUNKS*4 floats (8 f16 each)
#define WS_BPL     (WS_BPH + BP_CHUNKS*4)

typedef _Float16 f16;
typedef f16 f16x8 __attribute__((ext_vector_type(8)));
typedef float f32x4 __attribute__((ext_vector_type(4)));

typedef const __attribute__((address_space(1))) void GAS;
typedef __attribute__((address_space(3))) void LAS;

#define SBAR()  __builtin_amdgcn_s_barrier()
#define SCHED() __builtin_amdgcn_sched_barrier(0)

// ---------------- Phase 0: class norms ----------------
__global__ __launch_bounds__(256) void cls_norms(const float* __restrict__ cls,
                                                 float* __restrict__ ws)
{
    int c = blockIdx.x;
    const float* row = cls + (size_t)c * DDIM;
    float s = 0.f;
    for (int d = threadIdx.x; d < DDIM; d += 256) {
        float v = row[d];
        s = fmaf(v, v, s);
    }
    #pragma unroll
    for (int off = 32; off; off >>= 1) s += __shfl_xor(s, off, 64);
    __shared__ float red[4];
    int w = threadIdx.x >> 6, l = threadIdx.x & 63;
    if (l == 0) red[w] = s;
    __syncthreads();
    if (threadIdx.x == 0) {
        float t = red[0] + red[1] + red[2] + red[3];
        ws[WS_NORMCLS + c] = sqrtf(t);
    }
}

// ---------------- Phase 0b: class_hvs -> fp16 hi/lo, chunked + col-XOR-swizzled ----------------
// chunk (k8, p) holds cls[col = p ^ (k8&7)][k8*8 .. +7]; zero-padded
__global__ __launch_bounds__(256) void prep_b(const float* __restrict__ cls,
                                              float* __restrict__ ws)
{
    int c = blockIdx.x * 256 + threadIdx.x;
    if (c >= BP_CHUNKS) return;
    int p = c & 127, k8 = c >> 7;
    int col = p ^ (k8 & 7);
    f16x8 hi, lo;
    #pragma unroll
    for (int j = 0; j < 8; ++j) {
        int k = k8 * 8 + j;
        float v = (col < NCLS && k < DDIM) ? cls[(size_t)col * DDIM + k] : 0.f;
        f16 h = (f16)v;
        hi[j] = h;
        lo[j] = (f16)(v - (float)h);
    }
    ((f16x8*)(ws + WS_BPH))[c] = hi;
    ((f16x8*)(ws + WS_BPL))[c] = lo;
}

// ---------------- Phase 1: MFMA GEMM, fp16 split, BM=64 BN=128 BK=64 ----------------
// grid (128, KSPLIT); 4 waves; wave w -> cols [32w, 32w+32)
__global__ __launch_bounds__(256, 2) void gemm_mfma(const float* __restrict__ enc,
                                                    float* __restrict__ ws)
{
    __shared__ f16 Ah[8*64*8], Al[8*64*8];       // [kg 0..7][row^kg][8]  (8KB each)
    __shared__ f16 Bh[2][8*128*8], Bl[2][8*128*8]; // [kg][colslot][8]    (16KB each buf)

    int tid = threadIdx.x;
    int w = __builtin_amdgcn_readfirstlane(tid >> 6);
    int l = tid & 63;
    int lane15 = l & 15, lg = l >> 4;
    int row_a = tid >> 2, q = tid & 3;            // A staging: thread = (row, k-quarter)
    int r0 = blockIdx.x * BM;
    int ky = blockIdx.y;
    int s_beg = (KSTEPS * ky) / KSPLIT;
    int s_end = (KSTEPS * (ky + 1)) / KSPLIT;

    const float* aptr = enc + (size_t)(r0 + row_a) * DDIM;
    const f16* bph = (const f16*)(ws + WS_BPH);
    const f16* bpl = (const f16*)(ws + WS_BPL);

    f32x4 acc[4][2] = {};
    float nsq = 0.f;
    float4 areg[4];

    // ---- prologue: A(s_beg) reg loads (addr-clamped, always 4 issues) ----
    {
        int kb = s_beg * BK + q * 16;
        #pragma unroll
        for (int i = 0; i < 4; ++i) {
            int k = kb + 4 * i;
            areg[i] = *(const float4*)(aptr + ((k + 4 <= DDIM) ? k : 0));
        }
    }
    // ---- prologue: B(s_beg) gload_lds into buf0 (8 per wave) ----
    #pragma unroll
    for (int jj = 0; jj < 2; ++jj) {
        int kg = 2 * w + jj;
        size_t sg = ((size_t)(s_beg * 8 + kg)) * 1024;
        #pragma unroll
        for (int half = 0; half < 2; ++half) {
            __builtin_amdgcn_global_load_lds((GAS*)(bph + sg + half * 512 + l * 8),
                                             (LAS*)&Bh[0][kg * 1024 + half * 512], 16, 0, 0);
            __builtin_amdgcn_global_load_lds((GAS*)(bpl + sg + half * 512 + l * 8),
                                             (LAS*)&Bl[0][kg * 1024 + half * 512], 16, 0, 0);
        }
    }

    int nsteps = s_end - s_beg;
    for (int t = 0; t < nsteps; ++t) {
        int s = s_beg + t;
        int cur = t & 1;

        // ---- convert A(s) regs -> hi/lo, XOR-swizzled ds_write (waits A regs: vmcnt(8)) ----
        bool tail = (s == KSTEPS - 1);
        int kmax = DDIM - (s * BK + q * 16);   // valid elems for this thread (tail only)
        #pragma unroll
        for (int jj = 0; jj < 2; ++jj) {
            float4 a0 = areg[2 * jj], a1 = areg[2 * jj + 1];
            float v[8] = {a0.x, a0.y, a0.z, a0.w, a1.x, a1.y, a1.z, a1.w};
            if (tail) {
                #pragma unroll
                for (int j = 0; j < 8; ++j) v[j] = (jj * 8 + j < kmax) ? v[j] : 0.f;
            }
            f16x8 hv, lv;
            #pragma unroll
            for (int j = 0; j < 8; ++j) {
                f16 h = (f16)v[j];
                hv[j] = h;
                lv[j] = (f16)(v[j] - (float)h);
                nsq = fmaf(v[j], v[j], nsq);
            }
            int kg = 2 * q + jj;
            int off = kg * 512 + (row_a ^ kg) * 8;
            *(f16x8*)&Ah[off] = hv;
            *(f16x8*)&Al[off] = lv;
        }

        // ---- issue A(s+1) reg loads (4, addr-clamped) ----
        {
            int kb = (s + 1) * BK + q * 16;
            #pragma unroll
            for (int i = 0; i < 4; ++i) {
                int k = kb + 4 * i;
                areg[i] = *(const float4*)(aptr + ((k + 4 <= DDIM) ? k : 0));
            }
        }
        // ---- issue B(s+1) gload_lds into buf[cur^1] (8, index-clamped) ----
        {
            int spf = (s + 1 < KSTEPS) ? (s + 1) : (KSTEPS - 1);
            #pragma unroll
            for (int jj = 0; jj < 2; ++jj) {
                int kg = 2 * w + jj;
                size_t sg = ((size_t)(spf * 8 + kg)) * 1024;
                #pragma unroll
                for (int half = 0; half < 2; ++half) {
                    __builtin_amdgcn_global_load_lds((GAS*)(bph + sg + half * 512 + l * 8),
                        (LAS*)&Bh[cur ^ 1][kg * 1024 + half * 512], 16, 0, 0);
                    __builtin_amdgcn_global_load_lds((GAS*)(bpl + sg + half * 512 + l * 8),
                        (LAS*)&Bl[cur ^ 1][kg * 1024 + half * 512], 16, 0, 0);
                }
            }
        }

        SCHED();
        // B(s) (oldest 8) done; A(s+1)+B(s+1) (12) stay in flight; ds_writes drained
        asm volatile("s_waitcnt vmcnt(12) lgkmcnt(0)" ::: "memory");
        SCHED();
        SBAR();

        // ---- MFMA phase ----
        #pragma unroll
        for (int kf = 0; kf < 2; ++kf) {
            int kg = kf * 4 + lg;
            int c0 = (w * 32 + lane15) ^ (kg & 7);
            int c1 = (w * 32 + 16 + lane15) ^ (kg & 7);
            f16x8 bh0 = *(const f16x8*)&Bh[cur][kg * 1024 + c0 * 8];
            f16x8 bh1 = *(const f16x8*)&Bh[cur][kg * 1024 + c1 * 8];
            f16x8 bl0 = *(const f16x8*)&Bl[cur][kg * 1024 + c0 * 8];
            f16x8 bl1 = *(const f16x8*)&Bl[cur][kg * 1024 + c1 * 8];
            #pragma unroll
            for (int mt = 0; mt < 4; ++mt) {
                int ro = (mt * 16 + lane15) ^ kg;
                f16x8 ah = *(const f16x8*)&Ah[kg * 512 + ro * 8];
                f16x8 al = *(const f16x8*)&Al[kg * 512 + ro * 8];
                acc[mt][0] = __builtin_amdgcn_mfma_f32_16x16x32_f16(ah, bh0, acc[mt][0], 0, 0, 0);
                acc[mt][1] = __builtin_amdgcn_mfma_f32_16x16x32_f16(ah, bh1, acc[mt][1], 0, 0, 0);
                acc[mt][0] = __builtin_amdgcn_mfma_f32_16x16x32_f16(al, bh0, acc[mt][0], 0, 0, 0);
                acc[mt][1] = __builtin_amdgcn_mfma_f32_16x16x32_f16(al, bh1, acc[mt][1], 0, 0, 0);
                acc[mt][0] = __builtin_amdgcn_mfma_f32_16x16x32_f16(ah, bl0, acc[mt][0], 0, 0, 0);
                acc[mt][1] = __builtin_amdgcn_mfma_f32_16x16x32_f16(ah, bl1, acc[mt][1], 0, 0, 0);
            }
        }

        SCHED();
        SBAR();   // protect single-buffered A against next iteration's ds_write
    }

    // ---- epilogue: partial scores ----
    float* scp = ws + WS_SCP + (size_t)ky * SCORES_N;
    #pragma unroll
    for (int mt = 0; mt < 4; ++mt) {
        #pragma unroll
        for (int nt = 0; nt < 2; ++nt) {
            int gcol = w * 32 + nt * 16 + lane15;
            if (gcol < NCLS) {
                #pragma unroll
                for (int j = 0; j < 4; ++j) {
                    int grow = r0 + mt * 16 + lg * 4 + j;
                    scp[(size_t)grow * NCLS + gcol] = acc[mt][nt][j];
                }
            }
        }
    }

    // ---- row-norm partials: reduce across the 4 k-quarter threads of each row ----
    float tn = nsq;
    tn += __shfl_xor(tn, 1, 4);
    tn += __shfl_xor(tn, 2, 4);
    if (q == 0) ws[WS_NRM + (size_t)ky * NROWS + r0 + row_a] = tn;
}

// ---------------- Phase 2: finalize scores, argmax, build class lists ----------------
__global__ __launch_bounds__(256) void finalize(const int* __restrict__ targets,
                                                float* __restrict__ out,
                                                float* __restrict__ ws)
{
    int w = threadIdx.x >> 6, l = threadIdx.x & 63;
    int row = blockIdx.x * 4 + w;
    const float* scp = ws + WS_SCP;

    float n2 = 0.f;
    #pragma unroll
    for (int ky = 0; ky < KSPLIT; ++ky) n2 += ws[WS_NRM + (size_t)ky * NROWS + row];
    float ne = sqrtf(n2);

    float best; int bi;
    {
        int c = l;
        float dsum = 0.f;
        #pragma unroll
        for (int ky = 0; ky < KSPLIT; ++ky)
            dsum += scp[(size_t)ky * SCORES_N + (size_t)row * NCLS + c];
        float s = dsum / (ne * ws[WS_NORMCLS + c]);
        out[(size_t)row * NCLS + c] = s;
        best = s; bi = c;
    }
    if (l + 64 < NCLS) {
        int c = l + 64;
        float dsum = 0.f;
        #pragma unroll
        for (int ky = 0; ky < KSPLIT; ++ky)
            dsum += scp[(size_t)ky * SCORES_N + (size_t)row * NCLS + c];
        float s = dsum / (ne * ws[WS_NORMCLS + c]);
        out[(size_t)row * NCLS + c] = s;
        if (s > best) { best = s; bi = c; }   // ties keep smaller index
    }
    #pragma unroll
    for (int off = 32; off; off >>= 1) {
        float ov = __shfl_xor(best, off, 64);
        int   oi = __shfl_xor(bi, off, 64);
        if (ov > best || (ov == best && oi < bi)) { best = ov; bi = oi; }
    }
    if (l == 0) {
        int tgt = targets[row];
        if (tgt != bi) {
            int* wsi = (int*)ws;
            int p1 = atomicAdd(wsi + WS_CNT_T + tgt, 1);
            if (p1 < LISTCAP) wsi[WS_LIST_T + tgt * LISTCAP + p1] = row;
            int p2 = atomicAdd(wsi + WS_CNT_P + bi, 1);
            if (p2 < LISTCAP) wsi[WS_LIST_P + bi * LISTCAP + p2] = row;
        }
    }
}

// ---------------- Phase 3: perceptron update ----------------
__global__ __launch_bounds__(256) void update(const float* __restrict__ enc,
                                              const float* __restrict__ cls,
                                              float* __restrict__ out,
                                              const float* __restrict__ ws)
{
    int c = blockIdx.y;
    int d = blockIdx.x * 256 + threadIdx.x;
    if (d >= DDIM) return;
    const int* wsi = (const int*)ws;

    float acc = 0.f;
    int nt = wsi[WS_CNT_T + c]; nt = nt < LISTCAP ? nt : LISTCAP;
    for (int i = 0; i < nt; ++i) {
        int n = wsi[WS_LIST_T + c * LISTCAP + i];
        acc += enc[(size_t)n * DDIM + d];
    }
    int np = wsi[WS_CNT_P + c]; np = np < LISTCAP ? np : LISTCAP;
    for (int i = 0; i < np; ++i) {
        int n = wsi[WS_LIST_P + c * LISTCAP + i];
        acc -= enc[(size_t)n * DDIM + d];
    }
    out[SCORES_N + (size_t)c * DDIM + d] = cls[(size_t)c * DDIM + d] + acc;
}

// ---------------- launch ----------------
extern "C" void kernel_launch(void* const* d_in, const int* in_sizes, int n_in,
                              void* d_out, int out_size, void* d_ws, size_t ws_size,
                              hipStream_t stream)
{
    const float* enc = (const float*)d_in[0];
    const float* cls = (const float*)d_in[1];
    const int*   tgt = (const int*)d_in[2];
    float* out = (float*)d_out;
    float* ws  = (float*)d_ws;

    hipMemsetAsync((char*)d_ws + (size_t)WS_CNT_T * 4, 0, 256 * 4, stream);

    cls_norms<<<NCLS, 256, 0, stream>>>(cls, ws);
    prep_b<<<(BP_CHUNKS + 255) / 256, 256, 0, stream>>>(cls, ws);

    dim3 g1(NROWS / BM, KSPLIT);
    gemm_mfma<<<g1, 256, 0, stream>>>(enc, ws);

    finalize<<<NROWS / 4, 256, 0, stream>>>(tgt, out, ws);

    dim3 g3((DDIM + 255) / 256, NCLS);
    update<<<g3, 256, 0, stream>>>(enc, cls, out, ws);
}

// Round 4
// 334.961 us; speedup vs baseline: 2.5229x; 1.0316x over previous
//
#include <hip/hip_runtime.h>
#include <hip/hip_bf16.h>
#include <math.h>

#define NROWS 8192
#define DDIM  10000
#define NCLS  100
#define LISTCAP 512

#define KSPLIT 8
#define KSTEPS 157            // ceil(10000/64)
#define BM 64
#define BK 64

#define SCORES_N (NROWS*NCLS)
#define NCHUNK8 1256          // k-octets, padded to 10048
#define BP_CHUNKS (NCHUNK8*128)

// ws layout in float (4B) units
#define WS_NORMCLS 0                                   // 128
#define WS_NRM     128                                 // KSPLIT*NROWS
#define WS_SCP     (WS_NRM + KSPLIT*NROWS)             // KSPLIT*NROWS*NCLS
#define WS_CNT_T   (WS_SCP + KSPLIT*SCORES_N)          // 128
#define WS_CNT_P   (WS_CNT_T + 128)                    // 128
#define WS_LIST_T  (WS_CNT_P + 128)                    // NCLS*LISTCAP
#define WS_LIST_P  (WS_LIST_T + NCLS*LISTCAP)          // NCLS*LISTCAP
#define WS_BPH     (WS_LIST_P + NCLS*LISTCAP)          // BP_CHUNKS*4 floats (8 f16 each)
#define WS_BPL     (WS_BPH + BP_CHUNKS*4)

typedef _Float16 f16;
typedef f16 f16x8 __attribute__((ext_vector_type(8)));
typedef float f32x4 __attribute__((ext_vector_type(4)));

#define SBAR()  __builtin_amdgcn_s_barrier()
#define SCHED() __builtin_amdgcn_sched_barrier(0)

// ---------------- Phase 0: class norms (+ zero list counters) ----------------
__global__ __launch_bounds__(256) void cls_norms(const float* __restrict__ cls,
                                                 float* __restrict__ ws)
{
    if (blockIdx.x == 0) ((int*)ws)[WS_CNT_T + threadIdx.x] = 0;  // 256 ints: CNT_T + CNT_P

    int c = blockIdx.x;
    const float* row = cls + (size_t)c * DDIM;
    float s = 0.f;
    for (int d = threadIdx.x; d < DDIM; d += 256) {
        float v = row[d];
        s = fmaf(v, v, s);
    }
    #pragma unroll
    for (int off = 32; off; off >>= 1) s += __shfl_xor(s, off, 64);
    __shared__ float red[4];
    int w = threadIdx.x >> 6, l = threadIdx.x & 63;
    if (l == 0) red[w] = s;
    __syncthreads();
    if (threadIdx.x == 0) {
        float t = red[0] + red[1] + red[2] + red[3];
        ws[WS_NORMCLS + c] = sqrtf(t);
    }
}

// ---------------- Phase 0b: class_hvs -> fp16 hi/lo, chunked [k8][col][8] ----------------
__global__ __launch_bounds__(256) void prep_b(const float* __restrict__ cls,
                                              float* __restrict__ ws)
{
    int c = blockIdx.x * 256 + threadIdx.x;
    if (c >= BP_CHUNKS) return;
    int col = c & 127, k8 = c >> 7;
    f16x8 hi, lo;
    #pragma unroll
    for (int j = 0; j < 8; ++j) {
        int k = k8 * 8 + j;
        float v = (col < NCLS && k < DDIM) ? cls[(size_t)col * DDIM + k] : 0.f;
        f16 h = (f16)v;
        hi[j] = h;
        lo[j] = (f16)(v - (float)h);
    }
    ((f16x8*)(ws + WS_BPH))[c] = hi;
    ((f16x8*)(ws + WS_BPL))[c] = lo;
}

// ---------------- Phase 1: MFMA GEMM, fp16 split; A in LDS, B from L2 regs ----------------
// grid (128, KSPLIT); 4 waves; wave w -> cols [32w, 32w+32)
__global__ __launch_bounds__(256, 4) void gemm_mfma(const float* __restrict__ enc,
                                                    float* __restrict__ ws)
{
    __shared__ f16 Ah[8*64*8], Al[8*64*8];   // [kg 0..7][row^kg][8]  (8KB each)

    int tid = threadIdx.x;
    int w = __builtin_amdgcn_readfirstlane(tid >> 6);
    int l = tid & 63;
    int lane15 = l & 15, lg = l >> 4;
    int row_a = tid >> 2, q = tid & 3;        // A staging: thread = (row, k-quarter)
    int r0 = blockIdx.x * BM;
    int ky = blockIdx.y;
    int s_beg = (KSTEPS * ky) / KSPLIT;
    int s_end = (KSTEPS * (ky + 1)) / KSPLIT;

    const float* aptr = enc + (size_t)(r0 + row_a) * DDIM;
    const f16* bph = (const f16*)(ws + WS_BPH);
    const f16* bpl = (const f16*)(ws + WS_BPL);

    f32x4 acc[4][2] = {};
    float nsq = 0.f;
    float4 areg[4];

    // prologue: A(s_beg) reg loads (addr-clamped, always 4 issues)
    {
        int kb = s_beg * BK + q * 16;
        #pragma unroll
        for (int i = 0; i < 4; ++i) {
            int k = kb + 4 * i;
            areg[i] = *(const float4*)(aptr + ((k + 4 <= DDIM) ? k : 0));
        }
    }

    int nsteps = s_end - s_beg;
    for (int t = 0; t < nsteps; ++t) {
        int s = s_beg + t;

        // ---- convert A(s) regs -> hi/lo (VALU only; compiler waits A regs) ----
        bool tail = (s == KSTEPS - 1);
        int kmax = DDIM - (s * BK + q * 16);
        f16x8 hv[2], lv[2];
        #pragma unroll
        for (int jj = 0; jj < 2; ++jj) {
            float4 a0 = areg[2 * jj], a1 = areg[2 * jj + 1];
            float v[8] = {a0.x, a0.y, a0.z, a0.w, a1.x, a1.y, a1.z, a1.w};
            if (tail) {
                #pragma unroll
                for (int j = 0; j < 8; ++j) v[j] = (jj * 8 + j < kmax) ? v[j] : 0.f;
            }
            #pragma unroll
            for (int j = 0; j < 8; ++j) {
                f16 h = (f16)v[j];
                hv[jj][j] = h;
                lv[jj][j] = (f16)(v[j] - (float)h);
                nsq = fmaf(v[j], v[j], nsq);
            }
        }

        SCHED();
        asm volatile("s_waitcnt lgkmcnt(0)" ::: "memory");  // prior iter's ds_reads done
        SCHED();
        SBAR();                                             // all waves done reading A(s-1)

        // ---- ds_write A(s) (XOR-swizzled) ----
        #pragma unroll
        for (int jj = 0; jj < 2; ++jj) {
            int kg = 2 * q + jj;
            int off = kg * 512 + (row_a ^ kg) * 8;
            *(f16x8*)&Ah[off] = hv[jj];
            *(f16x8*)&Al[off] = lv[jj];
        }

        // ---- issue B(s) reg loads (8 x 16B, L2-resident) ----
        f16x8 bh_[2][2], bl_[2][2];
        #pragma unroll
        for (int kf = 0; kf < 2; ++kf) {
            int kg = kf * 4 + lg;
            size_t kb = ((size_t)(s * 8 + kg)) * 128;
            #pragma unroll
            for (int nt = 0; nt < 2; ++nt) {
                int col = w * 32 + nt * 16 + lane15;
                bh_[kf][nt] = *(const f16x8*)(bph + (kb + col) * 8);
                bl_[kf][nt] = *(const f16x8*)(bpl + (kb + col) * 8);
            }
        }
        // ---- issue A(s+1) reg loads (addr-clamped) ----
        {
            int kb = (s + 1) * BK + q * 16;
            #pragma unroll
            for (int i = 0; i < 4; ++i) {
                int k = kb + 4 * i;
                areg[i] = *(const float4*)(aptr + ((k + 4 <= DDIM) ? k : 0));
            }
        }

        SCHED();
        asm volatile("s_waitcnt lgkmcnt(0)" ::: "memory");  // ds_writes visible
        SCHED();
        SBAR();                                             // A(s) tile ready

        // ---- MFMA phase: ds_read A frags + 48 MFMA ----
        #pragma unroll
        for (int kf = 0; kf < 2; ++kf) {
            int kg = kf * 4 + lg;
            #pragma unroll
            for (int mt = 0; mt < 4; ++mt) {
                int ro = (mt * 16 + lane15) ^ kg;
                f16x8 ah = *(const f16x8*)&Ah[kg * 512 + ro * 8];
                f16x8 al = *(const f16x8*)&Al[kg * 512 + ro * 8];
                acc[mt][0] = __builtin_amdgcn_mfma_f32_16x16x32_f16(ah, bh_[kf][0], acc[mt][0], 0, 0, 0);
                acc[mt][1] = __builtin_amdgcn_mfma_f32_16x16x32_f16(ah, bh_[kf][1], acc[mt][1], 0, 0, 0);
                acc[mt][0] = __builtin_amdgcn_mfma_f32_16x16x32_f16(al, bh_[kf][0], acc[mt][0], 0, 0, 0);
                acc[mt][1] = __builtin_amdgcn_mfma_f32_16x16x32_f16(al, bh_[kf][1], acc[mt][1], 0, 0, 0);
                acc[mt][0] = __builtin_amdgcn_mfma_f32_16x16x32_f16(ah, bl_[kf][0], acc[mt][0], 0, 0, 0);
                acc[mt][1] = __builtin_amdgcn_mfma_f32_16x16x32_f16(ah, bl_[kf][1], acc[mt][1], 0, 0, 0);
            }
        }
    }

    // ---- epilogue: partial scores ----
    float* scp = ws + WS_SCP + (size_t)ky * SCORES_N;
    #pragma unroll
    for (int mt = 0; mt < 4; ++mt) {
        #pragma unroll
        for (int nt = 0; nt < 2; ++nt) {
            int gcol = w * 32 + nt * 16 + lane15;
            if (gcol < NCLS) {
                #pragma unroll
                for (int j = 0; j < 4; ++j) {
                    int grow = r0 + mt * 16 + lg * 4 + j;
                    scp[(size_t)grow * NCLS + gcol] = acc[mt][nt][j];
                }
            }
        }
    }

    // ---- row-norm partials: reduce across the 4 k-quarter threads of each row ----
    float tn = nsq;
    tn += __shfl_xor(tn, 1, 4);
    tn += __shfl_xor(tn, 2, 4);
    if (q == 0) ws[WS_NRM + (size_t)ky * NROWS + r0 + row_a] = tn;
}

// ---------------- Phase 2: finalize scores, argmax, build class lists ----------------
__global__ __launch_bounds__(256) void finalize(const int* __restrict__ targets,
                                                float* __restrict__ out,
                                                float* __restrict__ ws)
{
    int w = threadIdx.x >> 6, l = threadIdx.x & 63;
    int row = blockIdx.x * 4 + w;
    const float* scp = ws + WS_SCP;

    float n2 = 0.f;
    #pragma unroll
    for (int ky = 0; ky < KSPLIT; ++ky) n2 += ws[WS_NRM + (size_t)ky * NROWS + row];
    float ne = sqrtf(n2);

    float best; int bi;
    {
        int c = l;
        float dsum = 0.f;
        #pragma unroll
        for (int ky = 0; ky < KSPLIT; ++ky)
            dsum += scp[(size_t)ky * SCORES_N + (size_t)row * NCLS + c];
        float s = dsum / (ne * ws[WS_NORMCLS + c]);
        out[(size_t)row * NCLS + c] = s;
        best = s; bi = c;
    }
    if (l + 64 < NCLS) {
        int c = l + 64;
        float dsum = 0.f;
        #pragma unroll
        for (int ky = 0; ky < KSPLIT; ++ky)
            dsum += scp[(size_t)ky * SCORES_N + (size_t)row * NCLS + c];
        float s = dsum / (ne * ws[WS_NORMCLS + c]);
        out[(size_t)row * NCLS + c] = s;
        if (s > best) { best = s; bi = c; }   // ties keep smaller index
    }
    #pragma unroll
    for (int off = 32; off; off >>= 1) {
        float ov = __shfl_xor(best, off, 64);
        int   oi = __shfl_xor(bi, off, 64);
        if (ov > best || (ov == best && oi < bi)) { best = ov; bi = oi; }
    }
    if (l == 0) {
        int tgt = targets[row];
        if (tgt != bi) {
            int* wsi = (int*)ws;
            int p1 = atomicAdd(wsi + WS_CNT_T + tgt, 1);
            if (p1 < LISTCAP) wsi[WS_LIST_T + tgt * LISTCAP + p1] = row;
            int p2 = atomicAdd(wsi + WS_CNT_P + bi, 1);
            if (p2 < LISTCAP) wsi[WS_LIST_P + bi * LISTCAP + p2] = row;
        }
    }
}

// ---------------- Phase 3: perceptron update ----------------
__global__ __launch_bounds__(256) void update(const float* __restrict__ enc,
                                              const float* __restrict__ cls,
                                              float* __restrict__ out,
                                              const float* __restrict__ ws)
{
    int c = blockIdx.y;
    int d = blockIdx.x * 256 + threadIdx.x;
    if (d >= DDIM) return;
    const int* wsi = (const int*)ws;

    float acc = 0.f;
    int nt = wsi[WS_CNT_T + c]; nt = nt < LISTCAP ? nt : LISTCAP;
    for (int i = 0; i < nt; ++i) {
        int n = wsi[WS_LIST_T + c * LISTCAP + i];
        acc += enc[(size_t)n * DDIM + d];
    }
    int np = wsi[WS_CNT_P + c]; np = np < LISTCAP ? np : LISTCAP;
    for (int i = 0; i < np; ++i) {
        int n = wsi[WS_LIST_P + c * LISTCAP + i];
        acc -= enc[(size_t)n * DDIM + d];
    }
    out[SCORES_N + (size_t)c * DDIM + d] = cls[(size_t)c * DDIM + d] + acc;
}

// ---------------- launch ----------------
extern "C" void kernel_launch(void* const* d_in, const int* in_sizes, int n_in,
                              void* d_out, int out_size, void* d_ws, size_t ws_size,
                              hipStream_t stream)
{
    const float* enc = (const float*)d_in[0];
    const float* cls = (const float*)d_in[1];
    const int*   tgt = (const int*)d_in[2];
    float* out = (float*)d_out;
    float* ws  = (float*)d_ws;

    cls_norms<<<NCLS, 256, 0, stream>>>(cls, ws);
    prep_b<<<(BP_CHUNKS + 255) / 256, 256, 0, stream>>>(cls, ws);

    dim3 g1(NROWS / BM, KSPLIT);
    gemm_mfma<<<g1, 256, 0, stream>>>(enc, ws);

    finalize<<<NROWS / 4, 256, 0, stream>>>(tgt, out, ws);

    dim3 g3((DDIM + 255) / 256, NCLS);
    update<<<g3, 256, 0, stream>>>(enc, cls, out, ws);
}